// Round 19
// baseline (6282.874 us; speedup 1.0000x reference)
//
#include <hip/hip_runtime.h>
#include <math.h>

#define NG 128          // graphs
#define NPG 256         // nodes per graph
#define NN 32768        // total nodes
#define HDIM 256        // hidden
#define FIN 128         // in features

// ---------------- CSR build: block per graph, LDS counting sort ----------------
__global__ __launch_bounds__(256) void k_csr(const int* __restrict__ esrc,
                                             const int* __restrict__ edst, int EPG,
                                             int* __restrict__ rowptr, int* __restrict__ csr) {
    __shared__ int cnt[NPG];
    __shared__ int cur[NPG];
    __shared__ int wtot[4];
    int g = blockIdx.x, tid = threadIdx.x;
    cnt[tid] = 0;
    __syncthreads();
    int base = g * EPG;
    for (int e = base + tid; e < base + EPG; e += 256)
        atomicAdd(&cnt[edst[e] & (NPG - 1)], 1);
    __syncthreads();
    int v = cnt[tid];
    int lane = tid & 63, w4 = tid >> 6;
    int iv = v;
    for (int off = 1; off < 64; off <<= 1) {
        int t = __shfl_up(iv, off);
        if (lane >= off) iv += t;
    }
    if (lane == 63) wtot[w4] = iv;
    __syncthreads();
    int addv = 0;
    for (int i = 0; i < w4; i++) addv += wtot[i];
    int excl = iv + addv - v;
    rowptr[g * NPG + tid] = base + excl;
    cur[tid] = base + excl;
    if (g == 0 && tid == 0) rowptr[NN] = NG * EPG;
    __syncthreads();
    for (int e = base + tid; e < base + EPG; e += 256) {
        int d = edst[e] & (NPG - 1);
        int p = atomicAdd(&cur[d], 1);
        csr[p] = esrc[e];
    }
}

// XCD-locality swizzle
__device__ __forceinline__ int swz_block(int bid, int bpg) {
    int xcd = bid & 7, r = bid >> 3;
    int graph = xcd * (NG / 8) + r / bpg;
    int sub = r - (r / bpg) * bpg;
    return graph * bpg + sub;
}

// ---------------- fused sort + stage-1 aggregation: wave per node ----------------
__global__ __launch_bounds__(256) void k_sortagg(const float* __restrict__ x,
                                                 const int* __restrict__ rowptr,
                                                 int* __restrict__ csr,
                                                 float* __restrict__ xa) {
    __shared__ int skey[4][64];
    __shared__ float swgt[4][64];
    int blk = swz_block(blockIdx.x, NPG / 4);
    int w = threadIdx.x >> 6, lane = threadIdx.x & 63;
    int n = blk * 4 + w;
    int e0 = rowptr[n];
    int d = rowptr[n + 1] - e0;
    float ddst = rsqrtf((float)(1 + d));
    bool big = d > 64;
    if (!big) {
        int key = (lane < d) ? csr[e0 + lane] : 0x7fffffff;
        int rank = 0;
        for (int j = 0; j < d; j++) {
            int kj = __shfl(key, j);
            rank += (kj < key || (kj == key && j < lane)) ? 1 : 0;
        }
        if (lane < d) {
            csr[e0 + rank] = key;
            skey[w][rank] = key;
            swgt[w][rank] = rsqrtf((float)(1 + rowptr[key + 1] - rowptr[key])) * ddst;
        }
    } else if (lane == 0) {
        for (int a = e0 + 1; a < e0 + d; a++) {
            int key = csr[a];
            int b = a - 1;
            while (b >= e0 && csr[b] > key) { csr[b + 1] = csr[b]; b--; }
            csr[b + 1] = key;
        }
    }
    __syncthreads();
    const float2* x2 = reinterpret_cast<const float2*>(x);
    float di = ddst;
    float2 h = x2[(size_t)n * (FIN / 2) + lane];
    float self = di * di;
    float ax = h.x * self, ay = h.y * self;
    if (!big) {
        for (int j = 0; j < d; j++) {
            int s = skey[w][j];
            float we = swgt[w][j];
            float2 hs = x2[(size_t)s * (FIN / 2) + lane];
            ax += hs.x * we; ay += hs.y * we;
        }
    } else {
        for (int e = e0; e < e0 + d; e++) {
            int s = csr[e];
            float we = rsqrtf((float)(1 + rowptr[s + 1] - rowptr[s])) * ddst;
            float2 hs = x2[(size_t)s * (FIN / 2) + lane];
            ax += hs.x * we; ay += hs.y * we;
        }
    }
    float2 o; o.x = ax; o.y = ay;
    reinterpret_cast<float2*>(xa)[(size_t)n * (FIN / 2) + lane] = o;
}

// ---------------- SGEMM (64x64, 4x4, pad 68, reg dbuf), compile-time K — stage 3 ----------------
#define BM 64
#define BN 64
#define BK 16
#define BMP 68
template<int K>
__global__ __launch_bounds__(256) void k_sgemm(const float* __restrict__ A,
                                               const float* __restrict__ B,
                                               float* __restrict__ C,
                                               const int* __restrict__ list,
                                               const float* __restrict__ tansel,
                                               const float* __restrict__ brelu,
                                               const float* __restrict__ wrel,
                                               const float* __restrict__ wroot,
                                               float* __restrict__ rrel4,
                                               float* __restrict__ rroot4) {
    const int N = HDIM;
    __shared__ float As[BK][BMP];
    __shared__ float Bs[BK][BN];
    int tid = threadIdx.x;
    int tx = tid & 15, ty = tid >> 4;
    int row0 = blockIdx.y * BM, col0 = blockIdx.x * BN;
    int lm = tid >> 2;
    int arow = list ? list[row0 + lm] : (row0 + lm);
    float tv = tansel ? tansel[row0 + lm] : 1.0f;
    int crow[4];
#pragma unroll
    for (int i = 0; i < 4; i++) {
        int r = row0 + ty * 4 + i;
        crow[i] = list ? list[r] : r;
    }
    int k4 = (tid & 3) * 4;
    int kkB = tid >> 4, cB = (tid & 15) * 4;
    float4 aP = *reinterpret_cast<const float4*>(&A[(size_t)arow * K + k4]);
    float4 bP = *reinterpret_cast<const float4*>(&B[(size_t)kkB * N + col0 + cB]);
    float acc[4][4] = {};
#pragma unroll
    for (int kb = 0; kb < K; kb += BK) {
        As[k4 + 0][lm] = aP.x * tv; As[k4 + 1][lm] = aP.y * tv;
        As[k4 + 2][lm] = aP.z * tv; As[k4 + 3][lm] = aP.w * tv;
        *reinterpret_cast<float4*>(&Bs[kkB][cB]) = bP;
        __syncthreads();
        if (kb + BK < K) {
            aP = *reinterpret_cast<const float4*>(&A[(size_t)arow * K + kb + BK + k4]);
            bP = *reinterpret_cast<const float4*>(&B[(size_t)(kb + BK + kkB) * N + col0 + cB]);
        }
#pragma unroll
        for (int k = 0; k < BK; k++) {
            float4 a = *reinterpret_cast<float4*>(&As[k][ty * 4]);
            float4 b = *reinterpret_cast<float4*>(&Bs[k][tx * 4]);
            float av[4] = {a.x, a.y, a.z, a.w};
            float bv[4] = {b.x, b.y, b.z, b.w};
#pragma unroll
            for (int i = 0; i < 4; i++)
#pragma unroll
                for (int j = 0; j < 4; j++) acc[i][j] += av[i] * bv[j];
        }
        __syncthreads();
    }
    float4 bb = make_float4(0.f, 0.f, 0.f, 0.f);
    if (brelu) bb = *reinterpret_cast<const float4*>(&brelu[col0 + tx * 4]);
    float4 wr = make_float4(0.f, 0.f, 0.f, 0.f), wo = wr;
    if (wrel) {
        wr = *reinterpret_cast<const float4*>(&wrel[col0 + tx * 4]);
        wo = *reinterpret_cast<const float4*>(&wroot[col0 + tx * 4]);
    }
#pragma unroll
    for (int i = 0; i < 4; i++) {
        float4 v = make_float4(acc[i][0], acc[i][1], acc[i][2], acc[i][3]);
        if (brelu) {
            v.x = fmaxf(v.x + bb.x, 0.f);
            v.y = fmaxf(v.y + bb.y, 0.f);
            v.z = fmaxf(v.z + bb.z, 0.f);
            v.w = fmaxf(v.w + bb.w, 0.f);
        }
        *reinterpret_cast<float4*>(&C[(size_t)crow[i] * N + col0 + tx * 4]) = v;
        if (wrel) {
            float s1 = v.x * wr.x + v.y * wr.y + v.z * wr.z + v.w * wr.w;
            float s2 = v.x * wo.x + v.y * wo.y + v.z * wo.z + v.w * wo.w;
            for (int off = 8; off > 0; off >>= 1) {
                s1 += __shfl_down(s1, off, 16);
                s2 += __shfl_down(s2, off, 16);
            }
            if (tx == 0) {
                rrel4[(size_t)crow[i] * 4 + blockIdx.x] = s1;
                rroot4[(size_t)crow[i] * 4 + blockIdx.x] = s2;
            }
        }
    }
}

// ---------------- dual N-tile SGEMM (64x128), compile-time K, stages 1 & 2 ----------------
template<int K>
__global__ __launch_bounds__(256) void k_sgemm2(const float* __restrict__ A,
                                                const float* __restrict__ B,
                                                float* __restrict__ C,
                                                const int* __restrict__ list,
                                                const float* __restrict__ tansel,
                                                const float* __restrict__ brelu,
                                                const float* __restrict__ wrel,
                                                const float* __restrict__ wroot,
                                                float* __restrict__ rrel4,
                                                float* __restrict__ rroot4) {
    const int N = HDIM;
    __shared__ float As[BK][BMP];
    __shared__ float Bs[BK][128];
    int tid = threadIdx.x;
    int tx = tid & 15, ty = tid >> 4;
    int row0 = blockIdx.y * BM, col0 = blockIdx.x * 128;
    int lm = tid >> 2;
    int arow = list ? list[row0 + lm] : (row0 + lm);
    float tv = tansel ? tansel[row0 + lm] : 1.0f;
    int crow[4];
#pragma unroll
    for (int i = 0; i < 4; i++) {
        int r = row0 + ty * 4 + i;
        crow[i] = list ? list[r] : r;
    }
    int k4 = (tid & 3) * 4;
    int kkB0 = tid >> 5, cB0 = (tid & 31) * 4;
    int kkB1 = (256 + tid) >> 5, cB1 = cB0;
    float4 aP = *reinterpret_cast<const float4*>(&A[(size_t)arow * K + k4]);
    float4 bP0 = *reinterpret_cast<const float4*>(&B[(size_t)kkB0 * N + col0 + cB0]);
    float4 bP1 = *reinterpret_cast<const float4*>(&B[(size_t)kkB1 * N + col0 + cB1]);
    float acc0[4][4] = {};
    float acc1[4][4] = {};
#pragma unroll
    for (int kb = 0; kb < K; kb += BK) {
        As[k4 + 0][lm] = aP.x * tv; As[k4 + 1][lm] = aP.y * tv;
        As[k4 + 2][lm] = aP.z * tv; As[k4 + 3][lm] = aP.w * tv;
        *reinterpret_cast<float4*>(&Bs[kkB0][cB0]) = bP0;
        *reinterpret_cast<float4*>(&Bs[kkB1][cB1]) = bP1;
        __syncthreads();
        if (kb + BK < K) {
            aP = *reinterpret_cast<const float4*>(&A[(size_t)arow * K + kb + BK + k4]);
            bP0 = *reinterpret_cast<const float4*>(&B[(size_t)(kb + BK + kkB0) * N + col0 + cB0]);
            bP1 = *reinterpret_cast<const float4*>(&B[(size_t)(kb + BK + kkB1) * N + col0 + cB1]);
        }
#pragma unroll
        for (int k = 0; k < BK; k++) {
            float4 a = *reinterpret_cast<float4*>(&As[k][ty * 4]);
            float4 b0 = *reinterpret_cast<float4*>(&Bs[k][tx * 4]);
            float4 b1 = *reinterpret_cast<float4*>(&Bs[k][64 + tx * 4]);
            float av[4] = {a.x, a.y, a.z, a.w};
            float bv0[4] = {b0.x, b0.y, b0.z, b0.w};
            float bv1[4] = {b1.x, b1.y, b1.z, b1.w};
#pragma unroll
            for (int i = 0; i < 4; i++) {
#pragma unroll
                for (int j = 0; j < 4; j++) {
                    acc0[i][j] += av[i] * bv0[j];
                    acc1[i][j] += av[i] * bv1[j];
                }
            }
        }
        __syncthreads();
    }
#pragma unroll
    for (int half = 0; half < 2; half++) {
        int cbase = col0 + half * 64;
        float (*acc)[4] = half ? acc1 : acc0;
        float4 bb = make_float4(0.f, 0.f, 0.f, 0.f);
        if (brelu) bb = *reinterpret_cast<const float4*>(&brelu[cbase + tx * 4]);
        float4 wr = make_float4(0.f, 0.f, 0.f, 0.f), wo = wr;
        if (wrel) {
            wr = *reinterpret_cast<const float4*>(&wrel[cbase + tx * 4]);
            wo = *reinterpret_cast<const float4*>(&wroot[cbase + tx * 4]);
        }
        int cb = blockIdx.x * 2 + half;
#pragma unroll
        for (int i = 0; i < 4; i++) {
            float4 v = make_float4(acc[i][0], acc[i][1], acc[i][2], acc[i][3]);
            if (brelu) {
                v.x = fmaxf(v.x + bb.x, 0.f);
                v.y = fmaxf(v.y + bb.y, 0.f);
                v.z = fmaxf(v.z + bb.z, 0.f);
                v.w = fmaxf(v.w + bb.w, 0.f);
            }
            *reinterpret_cast<float4*>(&C[(size_t)crow[i] * N + cbase + tx * 4]) = v;
            if (wrel) {
                float s1 = v.x * wr.x + v.y * wr.y + v.z * wr.z + v.w * wr.w;
                float s2 = v.x * wo.x + v.y * wo.y + v.z * wo.z + v.w * wo.w;
                for (int off = 8; off > 0; off >>= 1) {
                    s1 += __shfl_down(s1, off, 16);
                    s2 += __shfl_down(s2, off, 16);
                }
                if (tx == 0) {
                    rrel4[(size_t)crow[i] * 4 + cb] = s1;
                    rroot4[(size_t)crow[i] * 4 + cb] = s2;
                }
            }
        }
    }
}

// stages 2/3: wave per ACTIVE node; edges prefetched in lanes, broadcast via shfl
__global__ __launch_bounds__(256) void k_gcn_agg(const float* __restrict__ hW,
                                                 const float* __restrict__ dis,
                                                 const int* __restrict__ rs,
                                                 const int* __restrict__ re,
                                                 const int* __restrict__ ccsr,
                                                 const float* __restrict__ cwedge,
                                                 const float* __restrict__ bias,
                                                 const int* __restrict__ list, int bpg,
                                                 const float* __restrict__ w_rel,
                                                 const float* __restrict__ w_root,
                                                 float* __restrict__ out,
                                                 float* __restrict__ r_rel,
                                                 float* __restrict__ r_root) {
    int blk = swz_block(blockIdx.x, bpg);
    int idx = blk * 4 + (threadIdx.x >> 6);
    int lane = threadIdx.x & 63;
    int wid = list[idx];
    float di = dis[wid];
    int e0 = rs[wid];
    int ne = re[wid] - e0;
    int pse = (lane < ne) ? ccsr[e0 + lane] : 0;
    float psw = (lane < ne) ? cwedge[e0 + lane] : 0.f;
    float4 h = *reinterpret_cast<const float4*>(&hW[(size_t)wid * HDIM + lane * 4]);
    float self = di * di;
    float ax = h.x * self, ay = h.y * self, az = h.z * self, aw = h.w * self;
    for (int j = 0; j < ne; j++) {
        int s = __shfl(pse, j);
        float w = __shfl(psw, j);
        float4 hs = *reinterpret_cast<const float4*>(&hW[(size_t)s * HDIM + lane * 4]);
        ax += hs.x * w; ay += hs.y * w; az += hs.z * w; aw += hs.w * w;
    }
    float4 b = *reinterpret_cast<const float4*>(&bias[lane * 4]);
    float4 o;
    o.x = fmaxf(ax + b.x, 0.f);
    o.y = fmaxf(ay + b.y, 0.f);
    o.z = fmaxf(az + b.z, 0.f);
    o.w = fmaxf(aw + b.w, 0.f);
    *reinterpret_cast<float4*>(&out[(size_t)wid * HDIM + lane * 4]) = o;
    float4 wr = *reinterpret_cast<const float4*>(&w_rel[lane * 4]);
    float4 wo = *reinterpret_cast<const float4*>(&w_root[lane * 4]);
    float s1 = o.x * wr.x + o.y * wr.y + o.z * wr.z + o.w * wr.w;
    float s2 = o.x * wo.x + o.y * wo.y + o.z * wo.z + o.w * wo.w;
    for (int off = 32; off > 0; off >>= 1) {
        s1 += __shfl_down(s1, off);
        s2 += __shfl_down(s2, off);
    }
    if (lane == 0) { r_rel[wid] = s1; r_root[wid] = s2; }
}

// ---------------- fused score + top-k + readout (+compact-CSR emit) ----------------
template<bool STAGE1, bool EMIT, bool FIRST>
__global__ __launch_bounds__(256) void k_topkpool(const float* __restrict__ dis,
                                                  const int* __restrict__ rs,
                                                  const int* __restrict__ re,
                                                  const int* __restrict__ csr_in,
                                                  const float* __restrict__ r_rel,
                                                  const float* __restrict__ r_root,
                                                  const float* __restrict__ rrel4,
                                                  const float* __restrict__ rroot4,
                                                  const float* __restrict__ b_rel, int k,
                                                  int* __restrict__ list,
                                                  float* __restrict__ tanselG,
                                                  const float* __restrict__ h,
                                                  float* __restrict__ z, float invk,
                                                  float* __restrict__ disN,
                                                  int* __restrict__ csN,
                                                  int* __restrict__ ceN,
                                                  int* __restrict__ ccsrN,
                                                  float* __restrict__ cwedgeN,
                                                  int EPG) {
    __shared__ float rrel[NPG];
    __shared__ __align__(16) float sc[NPG];
    __shared__ int sels[NPG];
    __shared__ float disn[NPG];
    __shared__ int newl[128];
    __shared__ float tvsel[128];
    __shared__ int wtot[4];
    __shared__ float4 red4_s[4][16];
    __shared__ float4 red4_m[4][16];
    int g = blockIdx.x >> 2, fc = blockIdx.x & 3;
    int tid = threadIdx.x;
    int lane = tid & 63, w4 = tid >> 6;
    int n = g * NPG + tid;
    bool act = STAGE1 ? true : (dis[n] > 0.f);
    float rr, ro;
    if (STAGE1) {
        float4 r4 = *reinterpret_cast<const float4*>(&rrel4[(size_t)n * 4]);
        float4 o4 = *reinterpret_cast<const float4*>(&rroot4[(size_t)n * 4]);
        rr = ((r4.x + r4.y) + r4.z) + r4.w;
        ro = ((o4.x + o4.y) + o4.z) + o4.w;
    } else {
        rr = act ? r_rel[n] : 0.f;
        ro = act ? r_root[n] : 0.f;
    }
    rrel[tid] = act ? rr : 0.f;
    __syncthreads();
    int e0 = rs[n], e1 = re[n];
    float my;
    if (act) {
        float s = b_rel[0] + ro;
        for (int e = e0; e < e1; e++) s += rrel[csr_in[e] & (NPG - 1)];
        my = s;
    } else {
        my = -INFINITY;
    }
    sc[tid] = my;
    __syncthreads();
    int cnt = 0;
    {
        const float4* sc4 = reinterpret_cast<const float4*>(sc);
        for (int jj = 0; jj < NPG / 4; jj++) {
            float4 v = sc4[jj];
            int j0 = jj * 4;
            cnt += (v.x > my || (v.x == my && (j0 + 0) < tid)) ? 1 : 0;
            cnt += (v.y > my || (v.y == my && (j0 + 1) < tid)) ? 1 : 0;
            cnt += (v.z > my || (v.z == my && (j0 + 2) < tid)) ? 1 : 0;
            cnt += (v.w > my || (v.w == my && (j0 + 3) < tid)) ? 1 : 0;
        }
    }
    int a = (cnt < k) ? 1 : 0;
    sels[tid] = a;
    int incl;
    {
        int v = a;
        for (int off = 1; off < 64; off <<= 1) {
            int t = __shfl_up(v, off);
            if (lane >= off) v += t;
        }
        if (lane == 63) wtot[w4] = v;
        __syncthreads();
        int addv = 0;
        for (int i = 0; i < w4; i++) addv += wtot[i];
        incl = v + addv;
    }
    if (a) {
        int rk = incl - 1;
        newl[rk] = tid;
        float t = tanhf(my);
        tvsel[rk] = t;
        if (fc == 0 && list) {
            list[g * k + rk] = n;
            tanselG[g * k + rk] = t;
        }
    }
    if (EMIT) {
        if (fc == 0) {
            int deg2 = 0;
            if (a) {
                for (int e = e0; e < e1; e++) deg2 += sels[csr_in[e] & (NPG - 1)];
            }
            float dn = a ? rsqrtf((float)(1 + deg2)) : 0.f;
            disn[tid] = dn;
            disN[n] = dn;
            __syncthreads();
            int v = deg2;
            for (int off = 1; off < 64; off <<= 1) {
                int t = __shfl_up(v, off);
                if (lane >= off) v += t;
            }
            if (lane == 63) wtot[w4] = v;
            __syncthreads();
            int addv = 0;
            for (int i = 0; i < w4; i++) addv += wtot[i];
            int start = g * EPG + (v + addv) - deg2;
            csN[n] = start;
            ceN[n] = start + deg2;
            if (a) {
                int p = start;
                for (int e = e0; e < e1; e++) {
                    int srcg = csr_in[e];
                    int j = srcg & (NPG - 1);
                    if (sels[j]) {
                        ccsrN[p] = srcg;
                        cwedgeN[p] = disn[j] * dn;
                        p++;
                    }
                }
            }
        }
    }
    __syncthreads();
    {
        int q = tid & 15, sub = (tid >> 4) & 3, y = tid >> 6;
        const float4* h4 = reinterpret_cast<const float4*>(h);
        float4 s4 = make_float4(0.f, 0.f, 0.f, 0.f);
        float4 m4 = make_float4(-INFINITY, -INFINITY, -INFINITY, -INFINITY);
        for (int idx = y * 4 + sub; idx < k; idx += 16) {
            int node = g * NPG + newl[idx];
            float t = tvsel[idx];
            float4 v = h4[(size_t)node * (HDIM / 4) + fc * 16 + q];
            v.x *= t; v.y *= t; v.z *= t; v.w *= t;
            s4.x += v.x; s4.y += v.y; s4.z += v.z; s4.w += v.w;
            m4.x = fmaxf(m4.x, v.x); m4.y = fmaxf(m4.y, v.y);
            m4.z = fmaxf(m4.z, v.z); m4.w = fmaxf(m4.w, v.w);
        }
#pragma unroll
        for (int off = 16; off <= 32; off <<= 1) {
            s4.x += __shfl_down(s4.x, off); s4.y += __shfl_down(s4.y, off);
            s4.z += __shfl_down(s4.z, off); s4.w += __shfl_down(s4.w, off);
            m4.x = fmaxf(m4.x, __shfl_down(m4.x, off));
            m4.y = fmaxf(m4.y, __shfl_down(m4.y, off));
            m4.z = fmaxf(m4.z, __shfl_down(m4.z, off));
            m4.w = fmaxf(m4.w, __shfl_down(m4.w, off));
        }
        if (sub == 0) { red4_s[y][q] = s4; red4_m[y][q] = m4; }
        __syncthreads();
        if (tid < 16) {
            float4 a0 = red4_s[0][tid], a1 = red4_s[1][tid];
            float4 a2 = red4_s[2][tid], a3 = red4_s[3][tid];
            float4 S;
            S.x = ((a0.x + a1.x) + a2.x) + a3.x;
            S.y = ((a0.y + a1.y) + a2.y) + a3.y;
            S.z = ((a0.z + a1.z) + a2.z) + a3.z;
            S.w = ((a0.w + a1.w) + a2.w) + a3.w;
            float4 b0 = red4_m[0][tid], b1 = red4_m[1][tid];
            float4 b2 = red4_m[2][tid], b3 = red4_m[3][tid];
            float4 M;
            M.x = fmaxf(fmaxf(b0.x, b1.x), fmaxf(b2.x, b3.x));
            M.y = fmaxf(fmaxf(b0.y, b1.y), fmaxf(b2.y, b3.y));
            M.z = fmaxf(fmaxf(b0.z, b1.z), fmaxf(b2.z, b3.z));
            M.w = fmaxf(fmaxf(b0.w, b1.w), fmaxf(b2.w, b3.w));
            float4 Mean = make_float4(S.x * invk, S.y * invk, S.z * invk, S.w * invk);
            float4* z4 = reinterpret_cast<float4*>(z);
            int zb_ = (g * 768 + fc * 64) / 4 + tid;
            if (FIRST) {
                z4[zb_] = Mean;
                z4[zb_ + 64] = M;
                z4[zb_ + 128] = S;
            } else {
                float4 c0 = z4[zb_], c1 = z4[zb_ + 64], c2 = z4[zb_ + 128];
                c0.x += Mean.x; c0.y += Mean.y; c0.z += Mean.z; c0.w += Mean.w;
                c1.x += M.x; c1.y += M.y; c1.z += M.z; c1.w += M.w;
                c2.x += S.x; c2.y += S.y; c2.z += S.z; c2.w += S.w;
                z4[zb_] = c0;
                z4[zb_ + 64] = c1;
                z4[zb_ + 128] = c2;
            }
        }
    }
}

// ---------------- fused MLP (partial-sum groupings fixed) ----------------
__global__ __launch_bounds__(256) void k_mlp(const float* __restrict__ z,
                                             const float* __restrict__ W1, const float* __restrict__ b1,
                                             const float* __restrict__ W2, const float* __restrict__ b2,
                                             const float* __restrict__ W3, const float* __restrict__ b3,
                                             float* __restrict__ out) {
    __shared__ float zb[768];
    __shared__ float t1[256];
    __shared__ float t2[128];
    __shared__ float t3[10];
    __shared__ float lse;
    int g = blockIdx.x, tid = threadIdx.x;
    zb[tid] = z[g * 768 + tid];
    zb[tid + 256] = z[g * 768 + 256 + tid];
    zb[tid + 512] = z[g * 768 + 512 + tid];
    __syncthreads();
    {
        int col = tid;
        float r0 = 0.f, r1 = 0.f, r2 = 0.f, r3 = 0.f;
        for (int i = 0;   i < 192; i++) r0 += zb[i] * W1[(size_t)i * 256 + col];
        for (int i = 192; i < 384; i++) r1 += zb[i] * W1[(size_t)i * 256 + col];
        for (int i = 384; i < 576; i++) r2 += zb[i] * W1[(size_t)i * 256 + col];
        for (int i = 576; i < 768; i++) r3 += zb[i] * W1[(size_t)i * 256 + col];
        t1[col] = fmaxf(r0 + r1 + r2 + r3 + b1[col], 0.f);
    }
    __syncthreads();
    if (tid < 128) {
        int col = tid;
        float r0 = 0.f, r1 = 0.f, r2 = 0.f, r3 = 0.f;
        for (int i = 0;   i < 64;  i++) r0 += t1[i] * W2[(size_t)i * 128 + col];
        for (int i = 64;  i < 128; i++) r1 += t1[i] * W2[(size_t)i * 128 + col];
        for (int i = 128; i < 192; i++) r2 += t1[i] * W2[(size_t)i * 128 + col];
        for (int i = 192; i < 256; i++) r3 += t1[i] * W2[(size_t)i * 128 + col];
        t2[col] = fmaxf(((r0 + r1) + r2) + r3 + b2[col], 0.f);
    }
    __syncthreads();
    if (tid < 10) {
        float v = b3[tid];
        for (int i = 0; i < 128; i++) v += t2[i] * W3[(size_t)i * 10 + tid];
        t3[tid] = v;
    }
    __syncthreads();
    if (tid == 0) {
        float m = t3[0];
        for (int c = 1; c < 10; c++) m = fmaxf(m, t3[c]);
        float se = 0.f;
        for (int c = 0; c < 10; c++) se += expf(t3[c] - m);
        lse = m + logf(se);
    }
    __syncthreads();
    if (tid < 10) out[g * 10 + tid] = t3[tid] - lse;
}

// ---------------- launcher ----------------
extern "C" void kernel_launch(void* const* d_in, const int* in_sizes, int n_in,
                              void* d_out, int out_size, void* d_ws, size_t ws_size,
                              hipStream_t stream) {
    const float* x        = (const float*)d_in[0];
    const int*   ei       = (const int*)d_in[1];
    const float* conv1_W  = (const float*)d_in[3];
    const float* conv1_b  = (const float*)d_in[4];
    const float* conv2_W  = (const float*)d_in[5];
    const float* conv2_b  = (const float*)d_in[6];
    const float* conv3_W  = (const float*)d_in[7];
    const float* conv3_b  = (const float*)d_in[8];
    const float* p1_relW  = (const float*)d_in[9];
    const float* p1_relb  = (const float*)d_in[10];
    const float* p1_rootW = (const float*)d_in[11];
    const float* p2_relW  = (const float*)d_in[12];
    const float* p2_relb  = (const float*)d_in[13];
    const float* p2_rootW = (const float*)d_in[14];
    const float* fc1_W    = (const float*)d_in[15];
    const float* fc1_b    = (const float*)d_in[16];
    const float* fc2_W    = (const float*)d_in[17];
    const float* fc2_b    = (const float*)d_in[18];
    const float* fc3_W    = (const float*)d_in[19];
    const float* fc3_b    = (const float*)d_in[20];
    float* out = (float*)d_out;

    const int E = in_sizes[1] / 2;
    const int EPG = E / NG;
    const int* e_src = ei;
    const int* e_dst = ei + E;

    // workspace layout
    char* base = (char*)d_ws;
    size_t off = 0;
    auto alloc = [&](size_t bytes) { size_t o = off; off = (off + bytes + 255) & ~(size_t)255; return o; };
    float* hW     = (float*)(base + alloc((size_t)NN * HDIM * 4));   // also xa (NN x FIN)
    float* hcur   = (float*)(base + alloc((size_t)NN * HDIM * 4));
    float* dis    = (float*)(base + alloc(NN * 4));   // stage-2 dis
    float* dis2   = (float*)(base + alloc(NN * 4));   // stage-3 dis
    float* r_rel  = (float*)(base + alloc(NN * 4));
    float* r_root = (float*)(base + alloc(NN * 4));
    float* rrel4  = (float*)(base + alloc((size_t)NN * 4 * 4));
    float* rroot4 = (float*)(base + alloc((size_t)NN * 4 * 4));
    int*   rowptr = (int*)(base + alloc((NN + 1) * 4));
    int*   csr    = (int*)(base + alloc((size_t)E * 4));
    int*   cs1    = (int*)(base + alloc(NN * 4));
    int*   ce1    = (int*)(base + alloc(NN * 4));
    int*   ccsr1  = (int*)(base + alloc((size_t)E * 4));
    float* cwdg1  = (float*)(base + alloc((size_t)E * 4));
    int*   cs2    = (int*)(base + alloc(NN * 4));
    int*   ce2    = (int*)(base + alloc(NN * 4));
    int*   ccsr2  = (int*)(base + alloc((size_t)E * 4));
    float* cwdg2  = (float*)(base + alloc((size_t)E * 4));
    float* z      = (float*)(base + alloc((size_t)NG * 768 * 4));
    int*   list1  = (int*)(base + alloc((size_t)NG * 128 * 4));
    int*   list2  = (int*)(base + alloc((size_t)NG * 64 * 4));
    float* tans1  = (float*)(base + alloc((size_t)NG * 128 * 4));
    float* tans2  = (float*)(base + alloc((size_t)NG * 64 * 4));

    // CSR build + fused sort/stage-1 aggregation
    k_csr<<<NG, 256, 0, stream>>>(e_src, e_dst, EPG, rowptr, csr);
    float* xa = hW;
    k_sortagg<<<NN / 4, 256, 0, stream>>>(x, rowptr, csr, xa);

    // ---- stage 1 ----
    {
        dim3 ggrid(HDIM / 128, NN / BM);
        k_sgemm2<FIN><<<ggrid, 256, 0, stream>>>(xa, conv1_W, hcur, nullptr, nullptr,
                                                 conv1_b, p1_relW, p1_rootW, rrel4, rroot4);
    }
    k_topkpool<true, true, true><<<NG * 4, 256, 0, stream>>>(
        nullptr, rowptr, rowptr + 1, csr, nullptr, nullptr, rrel4, rroot4, p1_relb, 128,
        list1, tans1, hcur, z, 1.0f / 128.0f, dis, cs1, ce1, ccsr1, cwdg1, EPG);

    // ---- stage 2 ----
    {
        dim3 ggrid(HDIM / 128, (NG * 128) / BM);
        k_sgemm2<HDIM><<<ggrid, 256, 0, stream>>>(hcur, conv2_W, hW, list1, tans1,
                                                  nullptr, nullptr, nullptr, nullptr, nullptr);
    }
    k_gcn_agg<<<(NG * 128) / 4, 256, 0, stream>>>(hW, dis, cs1, ce1, ccsr1, cwdg1, conv2_b,
                                                  list1, 32, p2_relW, p2_rootW,
                                                  hcur, r_rel, r_root);
    k_topkpool<false, true, false><<<NG * 4, 256, 0, stream>>>(
        dis, cs1, ce1, ccsr1, r_rel, r_root, nullptr, nullptr, p2_relb, 64,
        list2, tans2, hcur, z, 1.0f / 64.0f, dis2, cs2, ce2, ccsr2, cwdg2, EPG);

    // ---- stage 3 ----
    {
        dim3 ggrid(HDIM / BN, (NG * 64) / BM);
        k_sgemm<HDIM><<<ggrid, 256, 0, stream>>>(hcur, conv3_W, hW, list2, tans2, nullptr,
                                                 nullptr, nullptr, nullptr, nullptr);
    }
    k_gcn_agg<<<(NG * 64) / 4, 256, 0, stream>>>(hW, dis2, cs2, ce2, ccsr2, cwdg2, conv3_b,
                                                 list2, 16, p2_relW, p2_rootW,
                                                 hcur, r_rel, r_root);
    k_topkpool<false, false, false><<<NG * 4, 256, 0, stream>>>(
        dis2, cs2, ce2, ccsr2, r_rel, r_root, nullptr, nullptr, p2_relb, 32,
        nullptr, nullptr, hcur, z, 1.0f / 32.0f, nullptr, nullptr, nullptr, nullptr, nullptr, EPG);

    // ---- MLP ----
    k_mlp<<<NG, 256, 0, stream>>>(z, fc1_W, fc1_b, fc2_W, fc2_b, fc3_W, fc3_b, out);
}

// Round 20
// 254.356 us; speedup vs baseline: 24.7011x; 24.7011x over previous
//
#include <hip/hip_runtime.h>
#include <math.h>

#define NG 128          // graphs
#define NPG 256         // nodes per graph
#define NN 32768        // total nodes
#define HDIM 256        // hidden
#define FIN 128         // in features

// ---------------- CSR build: block per graph, LDS counting sort ----------------
__global__ __launch_bounds__(256) void k_csr(const int* __restrict__ esrc,
                                             const int* __restrict__ edst, int EPG,
                                             int* __restrict__ rowptr, int* __restrict__ csr) {
    __shared__ int cnt[NPG];
    __shared__ int cur[NPG];
    __shared__ int wtot[4];
    int g = blockIdx.x, tid = threadIdx.x;
    cnt[tid] = 0;
    __syncthreads();
    int base = g * EPG;
    for (int e = base + tid; e < base + EPG; e += 256)
        atomicAdd(&cnt[edst[e] & (NPG - 1)], 1);
    __syncthreads();
    int v = cnt[tid];
    int lane = tid & 63, w4 = tid >> 6;
    int iv = v;
    for (int off = 1; off < 64; off <<= 1) {
        int t = __shfl_up(iv, off);
        if (lane >= off) iv += t;
    }
    if (lane == 63) wtot[w4] = iv;
    __syncthreads();
    int addv = 0;
    for (int i = 0; i < w4; i++) addv += wtot[i];
    int excl = iv + addv - v;
    rowptr[g * NPG + tid] = base + excl;
    cur[tid] = base + excl;
    if (g == 0 && tid == 0) rowptr[NN] = NG * EPG;
    __syncthreads();
    for (int e = base + tid; e < base + EPG; e += 256) {
        int d = edst[e] & (NPG - 1);
        int p = atomicAdd(&cur[d], 1);
        csr[p] = esrc[e];
    }
}

// XCD-locality swizzle
__device__ __forceinline__ int swz_block(int bid, int bpg) {
    int xcd = bid & 7, r = bid >> 3;
    int graph = xcd * (NG / 8) + r / bpg;
    int sub = r - (r / bpg) * bpg;
    return graph * bpg + sub;
}

// ---------------- fused sort + stage-1 aggregation: wave per node ----------------
__global__ __launch_bounds__(256) void k_sortagg(const float* __restrict__ x,
                                                 const int* __restrict__ rowptr,
                                                 int* __restrict__ csr,
                                                 float* __restrict__ xa) {
    __shared__ int skey[4][64];
    __shared__ float swgt[4][64];
    int blk = swz_block(blockIdx.x, NPG / 4);
    int w = threadIdx.x >> 6, lane = threadIdx.x & 63;
    int n = blk * 4 + w;
    int e0 = rowptr[n];
    int d = rowptr[n + 1] - e0;
    float ddst = rsqrtf((float)(1 + d));
    bool big = d > 64;
    if (!big) {
        int key = (lane < d) ? csr[e0 + lane] : 0x7fffffff;
        int rank = 0;
        for (int j = 0; j < d; j++) {
            int kj = __shfl(key, j);
            rank += (kj < key || (kj == key && j < lane)) ? 1 : 0;
        }
        if (lane < d) {
            csr[e0 + rank] = key;
            skey[w][rank] = key;
            swgt[w][rank] = rsqrtf((float)(1 + rowptr[key + 1] - rowptr[key])) * ddst;
        }
    } else if (lane == 0) {
        for (int a = e0 + 1; a < e0 + d; a++) {
            int key = csr[a];
            int b = a - 1;
            while (b >= e0 && csr[b] > key) { csr[b + 1] = csr[b]; b--; }
            csr[b + 1] = key;
        }
    }
    __syncthreads();
    const float2* x2 = reinterpret_cast<const float2*>(x);
    float di = ddst;
    float2 h = x2[(size_t)n * (FIN / 2) + lane];
    float self = di * di;
    float ax = h.x * self, ay = h.y * self;
    if (!big) {
        for (int j = 0; j < d; j++) {
            int s = skey[w][j];
            float we = swgt[w][j];
            float2 hs = x2[(size_t)s * (FIN / 2) + lane];
            ax += hs.x * we; ay += hs.y * we;
        }
    } else {
        for (int e = e0; e < e0 + d; e++) {
            int s = csr[e];
            float we = rsqrtf((float)(1 + rowptr[s + 1] - rowptr[s])) * ddst;
            float2 hs = x2[(size_t)s * (FIN / 2) + lane];
            ax += hs.x * we; ay += hs.y * we;
        }
    }
    float2 o; o.x = ax; o.y = ay;
    reinterpret_cast<float2*>(xa)[(size_t)n * (FIN / 2) + lane] = o;
}

// ---------------- SGEMM (64x64, 4x4, pad 68, reg dbuf) — stage 3 ----------------
#define BM 64
#define BN 64
#define BK 16
#define BMP 68
__global__ __launch_bounds__(256) void k_sgemm(const float* __restrict__ A,
                                               const float* __restrict__ B,
                                               float* __restrict__ C, int K,
                                               const int* __restrict__ list,
                                               const float* __restrict__ tansel,
                                               const float* __restrict__ brelu,
                                               const float* __restrict__ wrel,
                                               const float* __restrict__ wroot,
                                               float* __restrict__ rrel4,
                                               float* __restrict__ rroot4) {
    const int N = HDIM;
    __shared__ float As[BK][BMP];
    __shared__ float Bs[BK][BN];
    int tid = threadIdx.x;
    int tx = tid & 15, ty = tid >> 4;
    int row0 = blockIdx.y * BM, col0 = blockIdx.x * BN;
    int lm = tid >> 2;
    int arow = list ? list[row0 + lm] : (row0 + lm);
    float tv = tansel ? tansel[row0 + lm] : 1.0f;
    int crow[4];
#pragma unroll
    for (int i = 0; i < 4; i++) {
        int r = row0 + ty * 4 + i;
        crow[i] = list ? list[r] : r;
    }
    int k4 = (tid & 3) * 4;
    int kkB = tid >> 4, cB = (tid & 15) * 4;
    float4 aP = *reinterpret_cast<const float4*>(&A[(size_t)arow * K + k4]);
    float4 bP = *reinterpret_cast<const float4*>(&B[(size_t)kkB * N + col0 + cB]);
    float acc[4][4] = {};
    for (int kb = 0; kb < K; kb += BK) {
        As[k4 + 0][lm] = aP.x * tv; As[k4 + 1][lm] = aP.y * tv;
        As[k4 + 2][lm] = aP.z * tv; As[k4 + 3][lm] = aP.w * tv;
        *reinterpret_cast<float4*>(&Bs[kkB][cB]) = bP;
        __syncthreads();
        if (kb + BK < K) {
            aP = *reinterpret_cast<const float4*>(&A[(size_t)arow * K + kb + BK + k4]);
            bP = *reinterpret_cast<const float4*>(&B[(size_t)(kb + BK + kkB) * N + col0 + cB]);
        }
#pragma unroll
        for (int k = 0; k < BK; k++) {
            float4 a = *reinterpret_cast<float4*>(&As[k][ty * 4]);
            float4 b = *reinterpret_cast<float4*>(&Bs[k][tx * 4]);
            float av[4] = {a.x, a.y, a.z, a.w};
            float bv[4] = {b.x, b.y, b.z, b.w};
#pragma unroll
            for (int i = 0; i < 4; i++)
#pragma unroll
                for (int j = 0; j < 4; j++) acc[i][j] += av[i] * bv[j];
        }
        __syncthreads();
    }
    float4 bb = make_float4(0.f, 0.f, 0.f, 0.f);
    if (brelu) bb = *reinterpret_cast<const float4*>(&brelu[col0 + tx * 4]);
    float4 wr = make_float4(0.f, 0.f, 0.f, 0.f), wo = wr;
    if (wrel) {
        wr = *reinterpret_cast<const float4*>(&wrel[col0 + tx * 4]);
        wo = *reinterpret_cast<const float4*>(&wroot[col0 + tx * 4]);
    }
#pragma unroll
    for (int i = 0; i < 4; i++) {
        float4 v = make_float4(acc[i][0], acc[i][1], acc[i][2], acc[i][3]);
        if (brelu) {
            v.x = fmaxf(v.x + bb.x, 0.f);
            v.y = fmaxf(v.y + bb.y, 0.f);
            v.z = fmaxf(v.z + bb.z, 0.f);
            v.w = fmaxf(v.w + bb.w, 0.f);
        }
        *reinterpret_cast<float4*>(&C[(size_t)crow[i] * N + col0 + tx * 4]) = v;
        if (wrel) {
            float s1 = v.x * wr.x + v.y * wr.y + v.z * wr.z + v.w * wr.w;
            float s2 = v.x * wo.x + v.y * wo.y + v.z * wo.z + v.w * wo.w;
            for (int off = 8; off > 0; off >>= 1) {
                s1 += __shfl_down(s1, off, 16);
                s2 += __shfl_down(s2, off, 16);
            }
            if (tx == 0) {
                rrel4[(size_t)crow[i] * 4 + blockIdx.x] = s1;
                rroot4[(size_t)crow[i] * 4 + blockIdx.x] = s2;
            }
        }
    }
}

// ---------------- dual N-tile SGEMM (64x128), stages 1 & 2 ----------------
__global__ __launch_bounds__(256) void k_sgemm2(const float* __restrict__ A,
                                                const float* __restrict__ B,
                                                float* __restrict__ C, int K,
                                                const int* __restrict__ list,
                                                const float* __restrict__ tansel,
                                                const float* __restrict__ brelu,
                                                const float* __restrict__ wrel,
                                                const float* __restrict__ wroot,
                                                float* __restrict__ rrel4,
                                                float* __restrict__ rroot4) {
    const int N = HDIM;
    __shared__ float As[BK][BMP];
    __shared__ float Bs[BK][128];
    int tid = threadIdx.x;
    int tx = tid & 15, ty = tid >> 4;
    int row0 = blockIdx.y * BM, col0 = blockIdx.x * 128;
    int lm = tid >> 2;
    int arow = list ? list[row0 + lm] : (row0 + lm);
    float tv = tansel ? tansel[row0 + lm] : 1.0f;
    int crow[4];
#pragma unroll
    for (int i = 0; i < 4; i++) {
        int r = row0 + ty * 4 + i;
        crow[i] = list ? list[r] : r;
    }
    int k4 = (tid & 3) * 4;
    int kkB0 = tid >> 5, cB0 = (tid & 31) * 4;
    int kkB1 = (256 + tid) >> 5, cB1 = cB0;
    float4 aP = *reinterpret_cast<const float4*>(&A[(size_t)arow * K + k4]);
    float4 bP0 = *reinterpret_cast<const float4*>(&B[(size_t)kkB0 * N + col0 + cB0]);
    float4 bP1 = *reinterpret_cast<const float4*>(&B[(size_t)kkB1 * N + col0 + cB1]);
    float acc0[4][4] = {};
    float acc1[4][4] = {};
    for (int kb = 0; kb < K; kb += BK) {
        As[k4 + 0][lm] = aP.x * tv; As[k4 + 1][lm] = aP.y * tv;
        As[k4 + 2][lm] = aP.z * tv; As[k4 + 3][lm] = aP.w * tv;
        *reinterpret_cast<float4*>(&Bs[kkB0][cB0]) = bP0;
        *reinterpret_cast<float4*>(&Bs[kkB1][cB1]) = bP1;
        __syncthreads();
        if (kb + BK < K) {
            aP = *reinterpret_cast<const float4*>(&A[(size_t)arow * K + kb + BK + k4]);
            bP0 = *reinterpret_cast<const float4*>(&B[(size_t)(kb + BK + kkB0) * N + col0 + cB0]);
            bP1 = *reinterpret_cast<const float4*>(&B[(size_t)(kb + BK + kkB1) * N + col0 + cB1]);
        }
#pragma unroll
        for (int k = 0; k < BK; k++) {
            float4 a = *reinterpret_cast<float4*>(&As[k][ty * 4]);
            float4 b0 = *reinterpret_cast<float4*>(&Bs[k][tx * 4]);
            float4 b1 = *reinterpret_cast<float4*>(&Bs[k][64 + tx * 4]);
            float av[4] = {a.x, a.y, a.z, a.w};
            float bv0[4] = {b0.x, b0.y, b0.z, b0.w};
            float bv1[4] = {b1.x, b1.y, b1.z, b1.w};
#pragma unroll
            for (int i = 0; i < 4; i++) {
#pragma unroll
                for (int j = 0; j < 4; j++) {
                    acc0[i][j] += av[i] * bv0[j];
                    acc1[i][j] += av[i] * bv1[j];
                }
            }
        }
        __syncthreads();
    }
#pragma unroll
    for (int half = 0; half < 2; half++) {
        int cbase = col0 + half * 64;
        float (*acc)[4] = half ? acc1 : acc0;
        float4 bb = make_float4(0.f, 0.f, 0.f, 0.f);
        if (brelu) bb = *reinterpret_cast<const float4*>(&brelu[cbase + tx * 4]);
        float4 wr = make_float4(0.f, 0.f, 0.f, 0.f), wo = wr;
        if (wrel) {
            wr = *reinterpret_cast<const float4*>(&wrel[cbase + tx * 4]);
            wo = *reinterpret_cast<const float4*>(&wroot[cbase + tx * 4]);
        }
        int cb = blockIdx.x * 2 + half;
#pragma unroll
        for (int i = 0; i < 4; i++) {
            float4 v = make_float4(acc[i][0], acc[i][1], acc[i][2], acc[i][3]);
            if (brelu) {
                v.x = fmaxf(v.x + bb.x, 0.f);
                v.y = fmaxf(v.y + bb.y, 0.f);
                v.z = fmaxf(v.z + bb.z, 0.f);
                v.w = fmaxf(v.w + bb.w, 0.f);
            }
            *reinterpret_cast<float4*>(&C[(size_t)crow[i] * N + cbase + tx * 4]) = v;
            if (wrel) {
                float s1 = v.x * wr.x + v.y * wr.y + v.z * wr.z + v.w * wr.w;
                float s2 = v.x * wo.x + v.y * wo.y + v.z * wo.z + v.w * wo.w;
                for (int off = 8; off > 0; off >>= 1) {
                    s1 += __shfl_down(s1, off, 16);
                    s2 += __shfl_down(s2, off, 16);
                }
                if (tx == 0) {
                    rrel4[(size_t)crow[i] * 4 + cb] = s1;
                    rroot4[(size_t)crow[i] * 4 + cb] = s2;
                }
            }
        }
    }
}

// stages 2/3: wave per ACTIVE node; edges prefetched in lanes, broadcast via shfl
__global__ __launch_bounds__(256) void k_gcn_agg(const float* __restrict__ hW,
                                                 const float* __restrict__ dis,
                                                 const int* __restrict__ rs,
                                                 const int* __restrict__ re,
                                                 const int* __restrict__ ccsr,
                                                 const float* __restrict__ cwedge,
                                                 const float* __restrict__ bias,
                                                 const int* __restrict__ list, int bpg,
                                                 const float* __restrict__ w_rel,
                                                 const float* __restrict__ w_root,
                                                 float* __restrict__ out,
                                                 float* __restrict__ r_rel,
                                                 float* __restrict__ r_root) {
    int blk = swz_block(blockIdx.x, bpg);
    int idx = blk * 4 + (threadIdx.x >> 6);
    int lane = threadIdx.x & 63;
    int wid = list[idx];
    float di = dis[wid];
    int e0 = rs[wid];
    int ne = re[wid] - e0;
    int pse = (lane < ne) ? ccsr[e0 + lane] : 0;
    float psw = (lane < ne) ? cwedge[e0 + lane] : 0.f;
    float4 h = *reinterpret_cast<const float4*>(&hW[(size_t)wid * HDIM + lane * 4]);
    float self = di * di;
    float ax = h.x * self, ay = h.y * self, az = h.z * self, aw = h.w * self;
    for (int j = 0; j < ne; j++) {
        int s = __shfl(pse, j);
        float w = __shfl(psw, j);
        float4 hs = *reinterpret_cast<const float4*>(&hW[(size_t)s * HDIM + lane * 4]);
        ax += hs.x * w; ay += hs.y * w; az += hs.z * w; aw += hs.w * w;
    }
    float4 b = *reinterpret_cast<const float4*>(&bias[lane * 4]);
    float4 o;
    o.x = fmaxf(ax + b.x, 0.f);
    o.y = fmaxf(ay + b.y, 0.f);
    o.z = fmaxf(az + b.z, 0.f);
    o.w = fmaxf(aw + b.w, 0.f);
    *reinterpret_cast<float4*>(&out[(size_t)wid * HDIM + lane * 4]) = o;
    float4 wr = *reinterpret_cast<const float4*>(&w_rel[lane * 4]);
    float4 wo = *reinterpret_cast<const float4*>(&w_root[lane * 4]);
    float s1 = o.x * wr.x + o.y * wr.y + o.z * wr.z + o.w * wr.w;
    float s2 = o.x * wo.x + o.y * wo.y + o.z * wo.z + o.w * wo.w;
    for (int off = 32; off > 0; off >>= 1) {
        s1 += __shfl_down(s1, off);
        s2 += __shfl_down(s2, off);
    }
    if (lane == 0) { r_rel[wid] = s1; r_root[wid] = s2; }
}

// ---------------- fused score + top-k + readout (+compact-CSR emit) ----------------
template<bool STAGE1, bool EMIT, bool FIRST>
__global__ __launch_bounds__(256) void k_topkpool(const float* __restrict__ dis,
                                                  const int* __restrict__ rs,
                                                  const int* __restrict__ re,
                                                  const int* __restrict__ csr_in,
                                                  const float* __restrict__ r_rel,
                                                  const float* __restrict__ r_root,
                                                  const float* __restrict__ rrel4,
                                                  const float* __restrict__ rroot4,
                                                  const float* __restrict__ b_rel, int k,
                                                  int* __restrict__ list,
                                                  float* __restrict__ tanselG,
                                                  const float* __restrict__ h,
                                                  float* __restrict__ z, float invk,
                                                  float* __restrict__ disN,
                                                  int* __restrict__ csN,
                                                  int* __restrict__ ceN,
                                                  int* __restrict__ ccsrN,
                                                  float* __restrict__ cwedgeN,
                                                  int EPG) {
    __shared__ float rrel[NPG];
    __shared__ __align__(16) float sc[NPG];
    __shared__ int sels[NPG];
    __shared__ float disn[NPG];
    __shared__ int newl[128];
    __shared__ float tvsel[128];
    __shared__ int wtot[4];
    __shared__ float4 red4_s[4][16];
    __shared__ float4 red4_m[4][16];
    int g = blockIdx.x >> 2, fc = blockIdx.x & 3;
    int tid = threadIdx.x;
    int lane = tid & 63, w4 = tid >> 6;
    int n = g * NPG + tid;
    bool act = STAGE1 ? true : (dis[n] > 0.f);
    float rr, ro;
    if (STAGE1) {
        float4 r4 = *reinterpret_cast<const float4*>(&rrel4[(size_t)n * 4]);
        float4 o4 = *reinterpret_cast<const float4*>(&rroot4[(size_t)n * 4]);
        rr = ((r4.x + r4.y) + r4.z) + r4.w;
        ro = ((o4.x + o4.y) + o4.z) + o4.w;
    } else {
        rr = act ? r_rel[n] : 0.f;
        ro = act ? r_root[n] : 0.f;
    }
    rrel[tid] = act ? rr : 0.f;
    __syncthreads();
    int e0 = rs[n], e1 = re[n];
    float my;
    if (act) {
        float s = b_rel[0] + ro;
        for (int e = e0; e < e1; e++) s += rrel[csr_in[e] & (NPG - 1)];
        my = s;
    } else {
        my = -INFINITY;
    }
    sc[tid] = my;
    __syncthreads();
    int cnt = 0;
    {
        const float4* sc4 = reinterpret_cast<const float4*>(sc);
        for (int jj = 0; jj < NPG / 4; jj++) {
            float4 v = sc4[jj];
            int j0 = jj * 4;
            cnt += (v.x > my || (v.x == my && (j0 + 0) < tid)) ? 1 : 0;
            cnt += (v.y > my || (v.y == my && (j0 + 1) < tid)) ? 1 : 0;
            cnt += (v.z > my || (v.z == my && (j0 + 2) < tid)) ? 1 : 0;
            cnt += (v.w > my || (v.w == my && (j0 + 3) < tid)) ? 1 : 0;
        }
    }
    int a = (cnt < k) ? 1 : 0;
    sels[tid] = a;
    int incl;
    {
        int v = a;
        for (int off = 1; off < 64; off <<= 1) {
            int t = __shfl_up(v, off);
            if (lane >= off) v += t;
        }
        if (lane == 63) wtot[w4] = v;
        __syncthreads();
        int addv = 0;
        for (int i = 0; i < w4; i++) addv += wtot[i];
        incl = v + addv;
    }
    if (a) {
        int rk = incl - 1;
        newl[rk] = tid;
        float t = tanhf(my);
        tvsel[rk] = t;
        if (fc == 0 && list) {
            list[g * k + rk] = n;
            tanselG[g * k + rk] = t;
        }
    }
    if (EMIT) {
        if (fc == 0) {
            int deg2 = 0;
            if (a) {
                for (int e = e0; e < e1; e++) deg2 += sels[csr_in[e] & (NPG - 1)];
            }
            float dn = a ? rsqrtf((float)(1 + deg2)) : 0.f;
            disn[tid] = dn;
            disN[n] = dn;
            __syncthreads();
            int v = deg2;
            for (int off = 1; off < 64; off <<= 1) {
                int t = __shfl_up(v, off);
                if (lane >= off) v += t;
            }
            if (lane == 63) wtot[w4] = v;
            __syncthreads();
            int addv = 0;
            for (int i = 0; i < w4; i++) addv += wtot[i];
            int start = g * EPG + (v + addv) - deg2;
            csN[n] = start;
            ceN[n] = start + deg2;
            if (a) {
                int p = start;
                for (int e = e0; e < e1; e++) {
                    int srcg = csr_in[e];
                    int j = srcg & (NPG - 1);
                    if (sels[j]) {
                        ccsrN[p] = srcg;
                        cwedgeN[p] = disn[j] * dn;
                        p++;
                    }
                }
            }
        }
    }
    __syncthreads();
    {
        int q = tid & 15, sub = (tid >> 4) & 3, y = tid >> 6;
        const float4* h4 = reinterpret_cast<const float4*>(h);
        float4 s4 = make_float4(0.f, 0.f, 0.f, 0.f);
        float4 m4 = make_float4(-INFINITY, -INFINITY, -INFINITY, -INFINITY);
        for (int idx = y * 4 + sub; idx < k; idx += 16) {
            int node = g * NPG + newl[idx];
            float t = tvsel[idx];
            float4 v = h4[(size_t)node * (HDIM / 4) + fc * 16 + q];
            v.x *= t; v.y *= t; v.z *= t; v.w *= t;
            s4.x += v.x; s4.y += v.y; s4.z += v.z; s4.w += v.w;
            m4.x = fmaxf(m4.x, v.x); m4.y = fmaxf(m4.y, v.y);
            m4.z = fmaxf(m4.z, v.z); m4.w = fmaxf(m4.w, v.w);
        }
#pragma unroll
        for (int off = 16; off <= 32; off <<= 1) {
            s4.x += __shfl_down(s4.x, off); s4.y += __shfl_down(s4.y, off);
            s4.z += __shfl_down(s4.z, off); s4.w += __shfl_down(s4.w, off);
            m4.x = fmaxf(m4.x, __shfl_down(m4.x, off));
            m4.y = fmaxf(m4.y, __shfl_down(m4.y, off));
            m4.z = fmaxf(m4.z, __shfl_down(m4.z, off));
            m4.w = fmaxf(m4.w, __shfl_down(m4.w, off));
        }
        if (sub == 0) { red4_s[y][q] = s4; red4_m[y][q] = m4; }
        __syncthreads();
        if (tid < 16) {
            float4 a0 = red4_s[0][tid], a1 = red4_s[1][tid];
            float4 a2 = red4_s[2][tid], a3 = red4_s[3][tid];
            float4 S;
            S.x = ((a0.x + a1.x) + a2.x) + a3.x;
            S.y = ((a0.y + a1.y) + a2.y) + a3.y;
            S.z = ((a0.z + a1.z) + a2.z) + a3.z;
            S.w = ((a0.w + a1.w) + a2.w) + a3.w;
            float4 b0 = red4_m[0][tid], b1 = red4_m[1][tid];
            float4 b2 = red4_m[2][tid], b3 = red4_m[3][tid];
            float4 M;
            M.x = fmaxf(fmaxf(b0.x, b1.x), fmaxf(b2.x, b3.x));
            M.y = fmaxf(fmaxf(b0.y, b1.y), fmaxf(b2.y, b3.y));
            M.z = fmaxf(fmaxf(b0.z, b1.z), fmaxf(b2.z, b3.z));
            M.w = fmaxf(fmaxf(b0.w, b1.w), fmaxf(b2.w, b3.w));
            float4 Mean = make_float4(S.x * invk, S.y * invk, S.z * invk, S.w * invk);
            float4* z4 = reinterpret_cast<float4*>(z);
            int zb_ = (g * 768 + fc * 64) / 4 + tid;
            if (FIRST) {
                z4[zb_] = Mean;
                z4[zb_ + 64] = M;
                z4[zb_ + 128] = S;
            } else {
                float4 c0 = z4[zb_], c1 = z4[zb_ + 64], c2 = z4[zb_ + 128];
                c0.x += Mean.x; c0.y += Mean.y; c0.z += Mean.z; c0.w += Mean.w;
                c1.x += M.x; c1.y += M.y; c1.z += M.z; c1.w += M.w;
                c2.x += S.x; c2.y += S.y; c2.z += S.z; c2.w += S.w;
                z4[zb_] = c0;
                z4[zb_ + 64] = c1;
                z4[zb_ + 128] = c2;
            }
        }
    }
}

// ---------------- fused MLP (partial-sum groupings fixed) ----------------
__global__ __launch_bounds__(256) void k_mlp(const float* __restrict__ z,
                                             const float* __restrict__ W1, const float* __restrict__ b1,
                                             const float* __restrict__ W2, const float* __restrict__ b2,
                                             const float* __restrict__ W3, const float* __restrict__ b3,
                                             float* __restrict__ out) {
    __shared__ float zb[768];
    __shared__ float t1[256];
    __shared__ float t2[128];
    __shared__ float t3[10];
    __shared__ float lse;
    int g = blockIdx.x, tid = threadIdx.x;
    zb[tid] = z[g * 768 + tid];
    zb[tid + 256] = z[g * 768 + 256 + tid];
    zb[tid + 512] = z[g * 768 + 512 + tid];
    __syncthreads();
    {
        int col = tid;
        float r0 = 0.f, r1 = 0.f, r2 = 0.f, r3 = 0.f;
        for (int i = 0;   i < 192; i++) r0 += zb[i] * W1[(size_t)i * 256 + col];
        for (int i = 192; i < 384; i++) r1 += zb[i] * W1[(size_t)i * 256 + col];
        for (int i = 384; i < 576; i++) r2 += zb[i] * W1[(size_t)i * 256 + col];
        for (int i = 576; i < 768; i++) r3 += zb[i] * W1[(size_t)i * 256 + col];
        t1[col] = fmaxf(r0 + r1 + r2 + r3 + b1[col], 0.f);
    }
    __syncthreads();
    if (tid < 128) {
        int col = tid;
        float r0 = 0.f, r1 = 0.f, r2 = 0.f, r3 = 0.f;
        for (int i = 0;   i < 64;  i++) r0 += t1[i] * W2[(size_t)i * 128 + col];
        for (int i = 64;  i < 128; i++) r1 += t1[i] * W2[(size_t)i * 128 + col];
        for (int i = 128; i < 192; i++) r2 += t1[i] * W2[(size_t)i * 128 + col];
        for (int i = 192; i < 256; i++) r3 += t1[i] * W2[(size_t)i * 128 + col];
        t2[col] = fmaxf(((r0 + r1) + r2) + r3 + b2[col], 0.f);
    }
    __syncthreads();
    if (tid < 10) {
        float v = b3[tid];
        for (int i = 0; i < 128; i++) v += t2[i] * W3[(size_t)i * 10 + tid];
        t3[tid] = v;
    }
    __syncthreads();
    if (tid == 0) {
        float m = t3[0];
        for (int c = 1; c < 10; c++) m = fmaxf(m, t3[c]);
        float se = 0.f;
        for (int c = 0; c < 10; c++) se += expf(t3[c] - m);
        lse = m + logf(se);
    }
    __syncthreads();
    if (tid < 10) out[g * 10 + tid] = t3[tid] - lse;
}

// ---------------- launcher ----------------
extern "C" void kernel_launch(void* const* d_in, const int* in_sizes, int n_in,
                              void* d_out, int out_size, void* d_ws, size_t ws_size,
                              hipStream_t stream) {
    const float* x        = (const float*)d_in[0];
    const int*   ei       = (const int*)d_in[1];
    const float* conv1_W  = (const float*)d_in[3];
    const float* conv1_b  = (const float*)d_in[4];
    const float* conv2_W  = (const float*)d_in[5];
    const float* conv2_b  = (const float*)d_in[6];
    const float* conv3_W  = (const float*)d_in[7];
    const float* conv3_b  = (const float*)d_in[8];
    const float* p1_relW  = (const float*)d_in[9];
    const float* p1_relb  = (const float*)d_in[10];
    const float* p1_rootW = (const float*)d_in[11];
    const float* p2_relW  = (const float*)d_in[12];
    const float* p2_relb  = (const float*)d_in[13];
    const float* p2_rootW = (const float*)d_in[14];
    const float* fc1_W    = (const float*)d_in[15];
    const float* fc1_b    = (const float*)d_in[16];
    const float* fc2_W    = (const float*)d_in[17];
    const float* fc2_b    = (const float*)d_in[18];
    const float* fc3_W    = (const float*)d_in[19];
    const float* fc3_b    = (const float*)d_in[20];
    float* out = (float*)d_out;

    const int E = in_sizes[1] / 2;
    const int EPG = E / NG;
    const int* e_src = ei;
    const int* e_dst = ei + E;

    // workspace layout
    char* base = (char*)d_ws;
    size_t off = 0;
    auto alloc = [&](size_t bytes) { size_t o = off; off = (off + bytes + 255) & ~(size_t)255; return o; };
    float* hW     = (float*)(base + alloc((size_t)NN * HDIM * 4));   // also xa (NN x FIN)
    float* hcur   = (float*)(base + alloc((size_t)NN * HDIM * 4));
    float* dis    = (float*)(base + alloc(NN * 4));   // stage-2 dis
    float* dis2   = (float*)(base + alloc(NN * 4));   // stage-3 dis
    float* r_rel  = (float*)(base + alloc(NN * 4));
    float* r_root = (float*)(base + alloc(NN * 4));
    float* rrel4  = (float*)(base + alloc((size_t)NN * 4 * 4));
    float* rroot4 = (float*)(base + alloc((size_t)NN * 4 * 4));
    int*   rowptr = (int*)(base + alloc((NN + 1) * 4));
    int*   csr    = (int*)(base + alloc((size_t)E * 4));
    int*   cs1    = (int*)(base + alloc(NN * 4));
    int*   ce1    = (int*)(base + alloc(NN * 4));
    int*   ccsr1  = (int*)(base + alloc((size_t)E * 4));
    float* cwdg1  = (float*)(base + alloc((size_t)E * 4));
    int*   cs2    = (int*)(base + alloc(NN * 4));
    int*   ce2    = (int*)(base + alloc(NN * 4));
    int*   ccsr2  = (int*)(base + alloc((size_t)E * 4));
    float* cwdg2  = (float*)(base + alloc((size_t)E * 4));
    float* z      = (float*)(base + alloc((size_t)NG * 768 * 4));
    int*   list1  = (int*)(base + alloc((size_t)NG * 128 * 4));
    int*   list2  = (int*)(base + alloc((size_t)NG * 64 * 4));
    float* tans1  = (float*)(base + alloc((size_t)NG * 128 * 4));
    float* tans2  = (float*)(base + alloc((size_t)NG * 64 * 4));

    // CSR build + fused sort/stage-1 aggregation
    k_csr<<<NG, 256, 0, stream>>>(e_src, e_dst, EPG, rowptr, csr);
    float* xa = hW;
    k_sortagg<<<NN / 4, 256, 0, stream>>>(x, rowptr, csr, xa);

    // ---- stage 1 ----
    {
        dim3 ggrid(HDIM / 128, NN / BM);
        k_sgemm2<<<ggrid, 256, 0, stream>>>(xa, conv1_W, hcur, FIN, nullptr, nullptr,
                                            conv1_b, p1_relW, p1_rootW, rrel4, rroot4);
    }
    k_topkpool<true, true, true><<<NG * 4, 256, 0, stream>>>(
        nullptr, rowptr, rowptr + 1, csr, nullptr, nullptr, rrel4, rroot4, p1_relb, 128,
        list1, tans1, hcur, z, 1.0f / 128.0f, dis, cs1, ce1, ccsr1, cwdg1, EPG);

    // ---- stage 2 ----
    {
        dim3 ggrid(HDIM / 128, (NG * 128) / BM);
        k_sgemm2<<<ggrid, 256, 0, stream>>>(hcur, conv2_W, hW, HDIM, list1, tans1,
                                            nullptr, nullptr, nullptr, nullptr, nullptr);
    }
    k_gcn_agg<<<(NG * 128) / 4, 256, 0, stream>>>(hW, dis, cs1, ce1, ccsr1, cwdg1, conv2_b,
                                                  list1, 32, p2_relW, p2_rootW,
                                                  hcur, r_rel, r_root);
    k_topkpool<false, true, false><<<NG * 4, 256, 0, stream>>>(
        dis, cs1, ce1, ccsr1, r_rel, r_root, nullptr, nullptr, p2_relb, 64,
        list2, tans2, hcur, z, 1.0f / 64.0f, dis2, cs2, ce2, ccsr2, cwdg2, EPG);

    // ---- stage 3 ----
    {
        dim3 ggrid(HDIM / BN, (NG * 64) / BM);
        k_sgemm<<<ggrid, 256, 0, stream>>>(hcur, conv3_W, hW, HDIM, list2, tans2, nullptr,
                                           nullptr, nullptr, nullptr, nullptr);
    }
    k_gcn_agg<<<(NG * 64) / 4, 256, 0, stream>>>(hW, dis2, cs2, ce2, ccsr2, cwdg2, conv3_b,
                                                 list2, 16, p2_relW, p2_rootW,
                                                 hcur, r_rel, r_root);
    k_topkpool<false, false, false><<<NG * 4, 256, 0, stream>>>(
        dis2, cs2, ce2, ccsr2, r_rel, r_root, nullptr, nullptr, p2_relb, 32,
        nullptr, nullptr, hcur, z, 1.0f / 32.0f, nullptr, nullptr, nullptr, nullptr, nullptr, EPG);

    // ---- MLP ----
    k_mlp<<<NG, 256, 0, stream>>>(z, fc1_W, fc1_b, fc2_W, fc2_b, fc3_W, fc3_b, out);
}